// Round 9
// baseline (246.324 us; speedup 1.0000x reference)
//
#include <hip/hip_runtime.h>
#include <hip/hip_bf16.h>

#define GSZ 36
static const int NX  = 16 * 32 * 224 * 224;     // 25,690,112
static const int NX4 = NX / 4;                  // 6,422,528 (NX % 4 == 0)
static const int NW  = 32 * 32 * 3 * 3;         // 9,216
static const int GXN = (NX + GSZ - 1) / GSZ;    // 713,615
static const int HWp = 224 * 224;               // 50,176 = 448 * 112

typedef short bf16x8 __attribute__((ext_vector_type(8)));
typedef float f32x4  __attribute__((ext_vector_type(4)));

// floor(n/36), exact for n < 2^31
__device__ __forceinline__ unsigned div36(unsigned n) {
    return (unsigned)(((unsigned long long)n * 954437177ull) >> 35);
}
// scale = 2^(floor(log2 m) - 7) via exponent field (m normal > 0)
__device__ __forceinline__ float scale_from_max(float m) {
    int e = (int)((__float_as_uint(m) >> 23) & 0xffu) - 127;
    return __uint_as_float((unsigned)(e + 120) << 23);
}
// 1/scale for power-of-two scale: bits = 0x7F000000 - scale_bits
__device__ __forceinline__ float inv_from_scale(float s) {
    return __uint_as_float(0x7F000000u - __float_as_uint(s));
}
__device__ __forceinline__ unsigned short f2bf(float f) {
    return (unsigned short)(__float_as_uint(f) >> 16);  // exact for BFP-8 values
}

// ---------- fused x: BFP-quantize (flat-36 groups) + NCHW->NHWC ----------
// Round 9: px-split blocks (224 px x 32 ci), thread owns ONE ci and 9 cover
// chunks in regs. LDS = 15.6 KB (pmax unions into tile) -> 8 blocks/CU = full
// 32 waves/CU occupancy (was 16). Groups straddling the 224-px edge get their
// scale from the full cover (chunks loaded past the span), so both neighboring
// blocks compute identical scales. Block (0,0) also quantizes the weights.
#define TST 228    // bf16 tile row stride (even; 456 B rows)
__global__ __launch_bounds__(256, 8) void k_quant_x_fused(const float* __restrict__ x,
                                                          unsigned short* __restrict__ xt,
                                                          const float* __restrict__ w,
                                                          unsigned short* __restrict__ wt) {
    __shared__ __align__(16) unsigned char raw[32 * TST * 2];    // 14,592 B
    unsigned short* tile = reinterpret_cast<unsigned short*>(raw);   // phase C/D
    float* pmax = reinterpret_cast<float*>(raw);                     // phase A/B (9,216 B)
    __shared__ float scl[32 * 8];                                    // 1,024 B

    int t = threadIdx.x;
    int b = blockIdx.y, hp = blockIdx.x;           // hp: 224-px span, 0..223
    int ci = t >> 3;                               // one ci per thread
    int l8 = t & 7;

    int F = (b * 32 + ci) * HWp + hp * 224;        // flat start of (ci, span); mult of 4
    int r = F - 36 * (int)div36((unsigned)F);      // F % 36 (multiple of 4)
    int base4 = (int)(((unsigned)(F - r)) >> 2);   // cover f4 base (group-aligned)

    // Phase A: 9 chunk loads (8x128B contiguous runs per instr); chunk max -> pmax
    f32x4 v[9];
    #pragma unroll
    for (int j = 0; j < 9; ++j) {
        int c = l8 + 8 * j;                        // cover chunk 0..71
        int f4 = base4 + c;
        f32x4 tv = {0.f, 0.f, 0.f, 0.f};
        if ((unsigned)f4 < (unsigned)NX4)
            tv = reinterpret_cast<const f32x4*>(x)[f4];
        v[j] = tv;
        pmax[ci * 72 + c] = fmaxf(fmaxf(fabsf(tv[0]), fabsf(tv[1])),
                                  fmaxf(fabsf(tv[2]), fabsf(tv[3])));
    }
    __syncthreads();

    // Phase B: 256 tasks = 32 ci x 8 groups; group max over 9 chunk-maxes
    {
        int bc = t >> 3, gi = t & 7;               // ci=bc, group gi
        const float* pp = &pmax[bc * 72 + 9 * gi];
        float m = pp[0];
        #pragma unroll
        for (int i = 1; i < 9; ++i) m = fmaxf(m, pp[i]);
        scl[bc * 8 + gi] = (m > 0.f) ? scale_from_max(m) : 0.f;
    }
    __syncthreads();

    // Phase C: quantize held regs, pack bf16 into tile (overwrites pmax region)
    #pragma unroll
    for (int j = 0; j < 9; ++j) {
        int c = l8 + 8 * j;
        int rel = 4 * c - r;                       // span-relative elem offset
        if ((unsigned)rel < 224u) {
            float s = scl[ci * 8 + ((c * 57) >> 9)];   // c/9 exact
            f32x4 q = v[j];
            if (s > 0.f) {
                float inv = inv_from_scale(s);
                #pragma unroll
                for (int k = 0; k < 4; ++k) q[k] = rintf(q[k] * inv) * s;
            } else {
                q = f32x4{0.f, 0.f, 0.f, 0.f};
            }
            uint2 o;
            o.x = (unsigned)f2bf(q[0]) | ((unsigned)f2bf(q[1]) << 16);
            o.y = (unsigned)f2bf(q[2]) | ((unsigned)f2bf(q[3]) << 16);
            *reinterpret_cast<uint2*>(&tile[ci * TST + rel]) = o;
        }
    }
    __syncthreads();

    // Phase D: 448 tasks of (2 px x 8 ci); 8 x ds_read_b32, 2 x 16B stores
    unsigned short* ob = xt + ((size_t)b * HWp + hp * 224) * 32;
    #pragma unroll
    for (int j = 0; j < 2; ++j) {
        int task = t + 256 * j;
        if (task < 448) {
            int px0 = (task >> 2) << 1;            // 0,2,...,222 (even)
            int c0 = (task & 3) * 8;
            unsigned rr[8];
            #pragma unroll
            for (int p = 0; p < 8; ++p)
                rr[p] = *reinterpret_cast<const unsigned*>(&tile[(c0 + p) * TST + px0]);
            unsigned ua[4], ub[4];
            #pragma unroll
            for (int p = 0; p < 4; ++p) {
                ua[p] = (rr[2*p] & 0xffffu) | (rr[2*p+1] << 16);
                ub[p] = (rr[2*p] >> 16)     | (rr[2*p+1] & 0xffff0000u);
            }
            *reinterpret_cast<uint4*>(ob + (size_t)px0 * 32 + c0) =
                make_uint4(ua[0], ua[1], ua[2], ua[3]);
            *reinterpret_cast<uint4*>(ob + (size_t)(px0 + 1) * 32 + c0) =
                make_uint4(ub[0], ub[1], ub[2], ub[3]);
        }
    }

    // merged k_quant_wt: block (0,0) only, one group per thread
    if (b == 0 && hp == 0) {
        int base = t * GSZ;
        float vw[GSZ];
        const float4* p = reinterpret_cast<const float4*>(w + base);
        #pragma unroll
        for (int i = 0; i < 9; ++i) {
            float4 tv = p[i];
            vw[4*i+0] = tv.x; vw[4*i+1] = tv.y; vw[4*i+2] = tv.z; vw[4*i+3] = tv.w;
        }
        float m = 0.0f;
        #pragma unroll
        for (int i = 0; i < GSZ; ++i) m = fmaxf(m, fabsf(vw[i]));
        if (m > 0.0f) {
            float s = scale_from_max(m), inv = inv_from_scale(s);
            #pragma unroll
            for (int i = 0; i < GSZ; ++i) vw[i] = rintf(vw[i] * inv) * s;
        }
        #pragma unroll
        for (int i = 0; i < GSZ; ++i) {
            int f = base + i;
            int co = f / 288, rem = f - co * 288;
            int cc = rem / 9, s = rem - cc * 9;
            wt[s * 1024 + co * 32 + cc] = f2bf(vw[i]);
        }
    }
}

// ---------- fused MFMA conv + out-quant epilogue ----------
// Block = 2 full rows x 224 px x 32 co for one b. XCD-aware bijective swizzle
// (1792 = 8*224). Groups fully inside the 448-px segment quantized here;
// 448-straddling groups (1/14) written raw, fixed by k_fixup.
#define PXS 40
#define COS 452
__global__ __launch_bounds__(256, 2) void k_conv_q(const unsigned short* __restrict__ xt,
                                                   const unsigned short* __restrict__ wt,
                                                   const float* __restrict__ bias,
                                                   float* __restrict__ out) {
    __shared__ __align__(16) unsigned char lraw[4 * 226 * PXS * 2];  // 72,320 B union
    unsigned short* xs = reinterpret_cast<unsigned short*>(lraw);    // [4][226][PXS] bf16
    float* ot = reinterpret_cast<float*>(lraw);                      // [32][COS] f32 (57,856 B)
    __shared__ float scl[32 * 12];
    __shared__ int rel0s[32], bnds[32];

    int tid  = threadIdx.x;
    int lane = tid & 63;
    int wid  = tid >> 6;
    // XCD-aware bijective remap: flat (y-major, x fastest) -> 8 chunks of 224
    int flat = blockIdx.y * 112 + blockIdx.x;
    int nf = (flat & 7) * 224 + (flat >> 3);
    int b     = nf / 112;          // XCD k handles b in {2k, 2k+1}
    int hpair = nf - b * 112;      // contiguous hpairs within an XCD
    int h0 = hpair * 2;

    // per-co group alignment within the 448-segment
    if (tid < 32) {
        int T = (b * 32 + tid) * HWp + hpair * 448;          // 448-aligned, mult of 4
        int r36 = T - 36 * (int)div36((unsigned)T);
        int rel0 = r36 ? 36 - r36 : 0;                       // first full-group offset
        rel0s[tid] = rel0;
        bnds[tid] = rel0 + 36 * (int)div36((unsigned)(448 - rel0));  // end of full zone
    }

    // stage 4 rows (h0-1..h0+2) x 226 px x 32 ci from NHWC
    const unsigned short* xb = xt + (size_t)b * HWp * 32;
    for (int k = 0; k < 15; ++k) {
        int q = tid + k * 256;
        if (q < 3616) {                        // 4*226*4 16B-chunks
            int r = ((q >> 3) * 145) >> 14;    // (q/8)/113, exact for q<3616
            int rem = q - r * 904;
            int p = rem >> 2, ch = rem & 3;
            int gh = h0 - 1 + r, gw = p - 1;
            uint4 val = make_uint4(0u, 0u, 0u, 0u);
            if ((unsigned)gh < 224u && (unsigned)gw < 224u)
                val = *reinterpret_cast<const uint4*>(xb + ((size_t)(gh * 224 + gw)) * 32 + ch * 8);
            *reinterpret_cast<uint4*>(&xs[(r * 226 + p) * PXS + ch * 8]) = val;
        }
    }

    // weight fragments (A-operand: m=lane&15=co, k=(lane>>4)*8+j=ci)
    bf16x8 Wf[9][2];
    #pragma unroll
    for (int s = 0; s < 9; ++s)
        #pragma unroll
        for (int hf = 0; hf < 2; ++hf)
            Wf[s][hf] = *reinterpret_cast<const bf16x8*>(
                wt + s * 1024 + (hf * 16 + (lane & 15)) * 32 + (lane >> 4) * 8);

    // acc init = bias
    int m4 = (lane >> 4) << 2;
    f32x4 acc[7][2];
    {
        f32x4 b0, b1;
        #pragma unroll
        for (int r = 0; r < 4; ++r) {
            b0[r] = bias[m4 + r];
            b1[r] = bias[16 + m4 + r];
        }
        #pragma unroll
        for (int i = 0; i < 7; ++i) { acc[i][0] = b0; acc[i][1] = b1; }
    }

    __syncthreads();

    // MFMA: wave owns 7 of 28 px fragments (frag f: row=f/14, col=(f%14)*16)
    int l15 = lane & 15;
    int kchunk = (lane >> 4) << 3;
    #pragma unroll
    for (int s = 0; s < 9; ++s) {
        int kh = s / 3, kw = s - kh * 3;
        #pragma unroll
        for (int i = 0; i < 7; ++i) {
            int f = wid * 7 + i;
            int row = (f >= 14) ? 1 : 0;
            int colf = (f - 14 * row) << 4;
            bf16x8 X = *reinterpret_cast<const bf16x8*>(
                &xs[((row + kh) * 226 + colf + l15 + kw) * PXS + kchunk]);
            acc[i][0] = __builtin_amdgcn_mfma_f32_16x16x32_bf16(Wf[s][0], X, acc[i][0], 0, 0, 0);
            acc[i][1] = __builtin_amdgcn_mfma_f32_16x16x32_bf16(Wf[s][1], X, acc[i][1], 0, 0, 0);
        }
    }
    __syncthreads();   // all xs reads done; lraw becomes ot

    // acc -> ot[co][px448]   (2-way bank aliasing only)
    #pragma unroll
    for (int i = 0; i < 7; ++i) {
        int f = wid * 7 + i;
        int row = (f >= 14) ? 1 : 0;
        int px = row * 224 + ((f - 14 * row) << 4) + l15;
        #pragma unroll
        for (int hf = 0; hf < 2; ++hf)
            #pragma unroll
            for (int r = 0; r < 4; ++r)
                ot[(hf * 16 + m4 + r) * COS + px] = acc[i][hf][r];
    }
    __syncthreads();

    // scales for full groups: 32 co x up to 12 groups
    #pragma unroll
    for (int it = 0; it < 2; ++it) {
        int task = tid + it * 256;
        if (task < 384) {
            int co = ((task >> 2) * 683) >> 11;          // task/12 = (task>>2)/3
            int k = task - co * 12;
            int base = rel0s[co] + 36 * k;
            if (base < bnds[co]) {
                const float* pp = &ot[co * COS + base];
                float m = 0.f;
                #pragma unroll
                for (int i = 0; i < 9; ++i) {
                    f32x4 vv = *reinterpret_cast<const f32x4*>(pp + 4 * i);
                    m = fmaxf(m, fmaxf(fmaxf(fabsf(vv[0]), fabsf(vv[1])),
                                       fmaxf(fabsf(vv[2]), fabsf(vv[3]))));
                }
                scl[co * 12 + k] = (m > 0.f) ? scale_from_max(m) : 0.f;
            }
        }
    }
    __syncthreads();

    // quantize + store: 3584 f32x4 chunks; each chunk lies in ONE group
    float* ob = out + (size_t)(b * 32) * HWp + h0 * 224;
    #pragma unroll
    for (int j = 0; j < 14; ++j) {
        int idx = tid + j * 256;
        int co = ((idx >> 4) * 2341) >> 14;              // idx/112 = (idx>>4)/7
        int c4 = idx - co * 112;
        int px0 = c4 * 4;
        f32x4 v = *reinterpret_cast<const f32x4*>(&ot[co * COS + px0]);
        int rz = px0 - rel0s[co];
        if ((unsigned)rz < (unsigned)(bnds[co] - rel0s[co])) {   // full-group zone
            int k = (int)div36((unsigned)rz);
            float s = scl[co * 12 + k];
            if (s > 0.f) {
                float inv = inv_from_scale(s);
                #pragma unroll
                for (int e = 0; e < 4; ++e) v[e] = rintf(v[e] * inv) * s;
            } else {
                v = f32x4{0.f, 0.f, 0.f, 0.f};
            }
        }
        // else: straddle zone -> raw value, k_fixup quantizes later
        *reinterpret_cast<f32x4*>(ob + (size_t)co * HWp + px0) = v;
    }
}

// ---------- fixup: quantize the 448-boundary-straddling groups in place ----------
// Straddle groups: g mod 112 in {12,24,37,49,62,74,87,99} (8 per 112).
__global__ __launch_bounds__(256) void k_fixup(float* __restrict__ buf) {
    int i = blockIdx.x * 256 + threadIdx.x;
    if (i >= 50976) return;
    const unsigned long long SP =
        12ull | (24ull << 7) | (37ull << 14) | (49ull << 21) |
        (62ull << 28) | (74ull << 35) | (87ull << 42) | (99ull << 49);
    int g = (i >> 3) * 112 + (int)((SP >> (7 * (i & 7))) & 127ull);
    if (g >= GXN) return;
    int f4 = 9 * g;                       // 36g/4
    f32x4 v[9];
    float m = 0.f;
    #pragma unroll
    for (int k = 0; k < 9; ++k) {
        f32x4 tv = {0.f, 0.f, 0.f, 0.f};
        if ((unsigned)(f4 + k) < (unsigned)NX4)
            tv = reinterpret_cast<const f32x4*>(buf)[f4 + k];
        v[k] = tv;
        m = fmaxf(m, fmaxf(fmaxf(fabsf(tv[0]), fabsf(tv[1])),
                           fmaxf(fabsf(tv[2]), fabsf(tv[3]))));
    }
    if (m > 0.f) {
        float s = scale_from_max(m), inv = inv_from_scale(s);
        #pragma unroll
        for (int k = 0; k < 9; ++k) {
            #pragma unroll
            for (int e = 0; e < 4; ++e) v[k][e] = rintf(v[k][e] * inv) * s;
            if ((unsigned)(f4 + k) < (unsigned)NX4)
                reinterpret_cast<f32x4*>(buf)[f4 + k] = v[k];
        }
    }
}

extern "C" void kernel_launch(void* const* d_in, const int* in_sizes, int n_in,
                              void* d_out, int out_size, void* d_ws, size_t ws_size,
                              hipStream_t stream) {
    (void)in_sizes; (void)n_in; (void)out_size; (void)ws_size;
    const float* x    = (const float*)d_in[0];
    const float* w    = (const float*)d_in[1];
    const float* bias = (const float*)d_in[2];
    float* out        = (float*)d_out;

    unsigned short* xt = (unsigned short*)d_ws;   // NX bf16 NHWC (51.4 MB)
    unsigned short* wt = xt + NX;                 // 9,216 bf16

    k_quant_x_fused<<<dim3(224, 16), 256, 0, stream>>>(x, xt, w, wt);
    k_conv_q<<<dim3(112, 16), 256, 0, stream>>>(xt, wt, bias, out);
    k_fixup<<<200, 256, 0, stream>>>(out);        // 50,976 straddle-group slots
}

// Round 10
// 241.113 us; speedup vs baseline: 1.0216x; 1.0216x over previous
//
#include <hip/hip_runtime.h>
#include <hip/hip_bf16.h>

#define GSZ 36
static const int NX  = 16 * 32 * 224 * 224;     // 25,690,112
static const int NX4 = NX / 4;                  // 6,422,528 (NX % 4 == 0)
static const int NW  = 32 * 32 * 3 * 3;         // 9,216
static const int GXN = (NX + GSZ - 1) / GSZ;    // 713,615
static const int HWp = 224 * 224;               // 50,176 = 448 * 112

typedef short bf16x8 __attribute__((ext_vector_type(8)));
typedef float f32x4  __attribute__((ext_vector_type(4)));

// floor(n/36), exact for n < 2^31
__device__ __forceinline__ unsigned div36(unsigned n) {
    return (unsigned)(((unsigned long long)n * 954437177ull) >> 35);
}
// scale = 2^(floor(log2 m) - 7) via exponent field (m normal > 0)
__device__ __forceinline__ float scale_from_max(float m) {
    int e = (int)((__float_as_uint(m) >> 23) & 0xffu) - 127;
    return __uint_as_float((unsigned)(e + 120) << 23);
}
// 1/scale for power-of-two scale: bits = 0x7F000000 - scale_bits
__device__ __forceinline__ float inv_from_scale(float s) {
    return __uint_as_float(0x7F000000u - __float_as_uint(s));
}
__device__ __forceinline__ unsigned short f2bf(float f) {
    return (unsigned short)(__float_as_uint(f) >> 16);  // exact for BFP-8 values
}

// ---------- fused x: BFP-quantize + NCHW->NHWC, SINGLE barrier ----------
// Round 10: px-split (224 px x 32 ci); the 8 threads sharing a ci are 8
// consecutive LANES of one wave, and the group-aligned cover is exactly
// 8 groups = 72 chunks. Chunk c = l8+8j belongs to group g = j - (j>l8)
// (closed form, 9 = 8+1), so per-group contributions and the quantize-scale
// lookup are STATICALLY indexed selects; group maxes reduce via 3-step
// shfl_xor within the 8-lane cluster. No pmax LDS, no scl LDS, no atomics,
// ONE barrier (before the transpose). Block (0,0) also quantizes weights.
#define TST 228    // bf16 tile row stride (456 B rows)
__global__ __launch_bounds__(256, 6) void k_quant_x_fused(const float* __restrict__ x,
                                                          unsigned short* __restrict__ xt,
                                                          const float* __restrict__ w,
                                                          unsigned short* __restrict__ wt) {
    __shared__ __align__(16) unsigned short tile[32 * TST];   // 14,592 B

    int t = threadIdx.x;
    int b = blockIdx.y, hp = blockIdx.x;           // hp: 224-px span, 0..223
    int ci = t >> 3;                               // one ci per 8-lane cluster
    int l8 = t & 7;

    int F = (b * 32 + ci) * HWp + hp * 224;        // flat start of (ci, span); mult of 4
    int r = F - 36 * (int)div36((unsigned)F);      // F % 36 (multiple of 4)
    int base4 = (int)(((unsigned)(F - r)) >> 2);   // cover f4 base (group-aligned)

    // loads: 9 chunks per lane, coalesced (8 lanes x 16B = 128B runs per ci)
    f32x4 v[9];
    float cm[9];
    #pragma unroll
    for (int j = 0; j < 9; ++j) {
        int f4 = base4 + l8 + 8 * j;
        f32x4 tv = {0.f, 0.f, 0.f, 0.f};
        if ((unsigned)f4 < (unsigned)NX4)
            tv = reinterpret_cast<const f32x4*>(x)[f4];
        v[j] = tv;
        cm[j] = fmaxf(fmaxf(fabsf(tv[0]), fabsf(tv[1])),
                      fmaxf(fabsf(tv[2]), fabsf(tv[3])));
    }

    // 8 group scales, all in registers (static indexing throughout)
    float S[8];
    #pragma unroll
    for (int g = 0; g < 8; ++g) {
        float a  = (g <= l8) ? cm[g]     : 0.0f;   // chunk j=g   (valid when g<=l8)
        float bb = (g >= l8) ? cm[g + 1] : 0.0f;   // chunk j=g+1 (valid when g>=l8)
        float c = fmaxf(a, bb);
        c = fmaxf(c, __shfl_xor(c, 1));
        c = fmaxf(c, __shfl_xor(c, 2));
        c = fmaxf(c, __shfl_xor(c, 4));            // 8-lane cluster reduction
        S[g] = (c > 0.f) ? scale_from_max(c) : 0.f;
    }

    // quantize held regs, pack bf16 into tile
    #pragma unroll
    for (int j = 0; j < 9; ++j) {
        int rel = 4 * (l8 + 8 * j) - r;            // span-relative elem offset
        if ((unsigned)rel < 224u) {
            float s = (j > l8) ? S[j - 1] : S[j];  // g = j - (j>l8), static indices
            f32x4 q = v[j];
            if (s > 0.f) {
                float inv = inv_from_scale(s);
                #pragma unroll
                for (int k = 0; k < 4; ++k) q[k] = rintf(q[k] * inv) * s;
            } else {
                q = f32x4{0.f, 0.f, 0.f, 0.f};
            }
            uint2 o;
            o.x = (unsigned)f2bf(q[0]) | ((unsigned)f2bf(q[1]) << 16);
            o.y = (unsigned)f2bf(q[2]) | ((unsigned)f2bf(q[3]) << 16);
            *reinterpret_cast<uint2*>(&tile[ci * TST + rel]) = o;
        }
    }
    __syncthreads();                               // the ONLY barrier

    // transpose phase: 448 tasks of (2 px x 8 ci); 8 x ds_read_b32, 2 x 16B stores
    unsigned short* ob = xt + ((size_t)b * HWp + hp * 224) * 32;
    #pragma unroll
    for (int j = 0; j < 2; ++j) {
        int task = t + 256 * j;
        if (task < 448) {
            int px0 = (task >> 2) << 1;            // 0,2,...,222 (even)
            int c0 = (task & 3) * 8;
            unsigned rr[8];
            #pragma unroll
            for (int p = 0; p < 8; ++p)
                rr[p] = *reinterpret_cast<const unsigned*>(&tile[(c0 + p) * TST + px0]);
            unsigned ua[4], ub[4];
            #pragma unroll
            for (int p = 0; p < 4; ++p) {
                ua[p] = (rr[2*p] & 0xffffu) | (rr[2*p+1] << 16);
                ub[p] = (rr[2*p] >> 16)     | (rr[2*p+1] & 0xffff0000u);
            }
            *reinterpret_cast<uint4*>(ob + (size_t)px0 * 32 + c0) =
                make_uint4(ua[0], ua[1], ua[2], ua[3]);
            *reinterpret_cast<uint4*>(ob + (size_t)(px0 + 1) * 32 + c0) =
                make_uint4(ub[0], ub[1], ub[2], ub[3]);
        }
    }

    // merged k_quant_wt: block (0,0) only, one group per thread
    if (b == 0 && hp == 0) {
        int base = t * GSZ;
        float vw[GSZ];
        const float4* p = reinterpret_cast<const float4*>(w + base);
        #pragma unroll
        for (int i = 0; i < 9; ++i) {
            float4 tv = p[i];
            vw[4*i+0] = tv.x; vw[4*i+1] = tv.y; vw[4*i+2] = tv.z; vw[4*i+3] = tv.w;
        }
        float m = 0.0f;
        #pragma unroll
        for (int i = 0; i < GSZ; ++i) m = fmaxf(m, fabsf(vw[i]));
        if (m > 0.0f) {
            float s = scale_from_max(m), inv = inv_from_scale(s);
            #pragma unroll
            for (int i = 0; i < GSZ; ++i) vw[i] = rintf(vw[i] * inv) * s;
        }
        #pragma unroll
        for (int i = 0; i < GSZ; ++i) {
            int f = base + i;
            int co = f / 288, rem = f - co * 288;
            int cc = rem / 9, s = rem - cc * 9;
            wt[s * 1024 + co * 32 + cc] = f2bf(vw[i]);
        }
    }
}

// ---------- fused MFMA conv + out-quant epilogue (R8 best-known version) ----------
// Block = 2 full rows x 224 px x 32 co for one b. XCD-aware bijective swizzle
// (1792 = 8*224). Groups fully inside the 448-px segment quantized here;
// 448-straddling groups (1/14) written raw, fixed by k_fixup.
#define PXS 40
#define COS 452
__global__ __launch_bounds__(256, 2) void k_conv_q(const unsigned short* __restrict__ xt,
                                                   const unsigned short* __restrict__ wt,
                                                   const float* __restrict__ bias,
                                                   float* __restrict__ out) {
    __shared__ __align__(16) unsigned char lraw[4 * 226 * PXS * 2];  // 72,320 B union
    unsigned short* xs = reinterpret_cast<unsigned short*>(lraw);    // [4][226][PXS] bf16
    float* ot = reinterpret_cast<float*>(lraw);                      // [32][COS] f32 (57,856 B)
    __shared__ float scl[32 * 12];
    __shared__ int rel0s[32], bnds[32];

    int tid  = threadIdx.x;
    int lane = tid & 63;
    int wid  = tid >> 6;
    // XCD-aware bijective remap: flat (y-major, x fastest) -> 8 chunks of 224
    int flat = blockIdx.y * 112 + blockIdx.x;
    int nf = (flat & 7) * 224 + (flat >> 3);
    int b     = nf / 112;          // XCD k handles b in {2k, 2k+1}
    int hpair = nf - b * 112;      // contiguous hpairs within an XCD
    int h0 = hpair * 2;

    // per-co group alignment within the 448-segment
    if (tid < 32) {
        int T = (b * 32 + tid) * HWp + hpair * 448;          // 448-aligned, mult of 4
        int r36 = T - 36 * (int)div36((unsigned)T);
        int rel0 = r36 ? 36 - r36 : 0;                       // first full-group offset
        rel0s[tid] = rel0;
        bnds[tid] = rel0 + 36 * (int)div36((unsigned)(448 - rel0));  // end of full zone
    }

    // stage 4 rows (h0-1..h0+2) x 226 px x 32 ci from NHWC
    const unsigned short* xb = xt + (size_t)b * HWp * 32;
    for (int k = 0; k < 15; ++k) {
        int q = tid + k * 256;
        if (q < 3616) {                        // 4*226*4 16B-chunks
            int r = ((q >> 3) * 145) >> 14;    // (q/8)/113, exact for q<3616
            int rem = q - r * 904;
            int p = rem >> 2, ch = rem & 3;
            int gh = h0 - 1 + r, gw = p - 1;
            uint4 val = make_uint4(0u, 0u, 0u, 0u);
            if ((unsigned)gh < 224u && (unsigned)gw < 224u)
                val = *reinterpret_cast<const uint4*>(xb + ((size_t)(gh * 224 + gw)) * 32 + ch * 8);
            *reinterpret_cast<uint4*>(&xs[(r * 226 + p) * PXS + ch * 8]) = val;
        }
    }

    // weight fragments (A-operand: m=lane&15=co, k=(lane>>4)*8+j=ci)
    bf16x8 Wf[9][2];
    #pragma unroll
    for (int s = 0; s < 9; ++s)
        #pragma unroll
        for (int hf = 0; hf < 2; ++hf)
            Wf[s][hf] = *reinterpret_cast<const bf16x8*>(
                wt + s * 1024 + (hf * 16 + (lane & 15)) * 32 + (lane >> 4) * 8);

    // acc init = bias
    int m4 = (lane >> 4) << 2;
    f32x4 acc[7][2];
    {
        f32x4 b0, b1;
        #pragma unroll
        for (int r = 0; r < 4; ++r) {
            b0[r] = bias[m4 + r];
            b1[r] = bias[16 + m4 + r];
        }
        #pragma unroll
        for (int i = 0; i < 7; ++i) { acc[i][0] = b0; acc[i][1] = b1; }
    }

    __syncthreads();

    // MFMA: wave owns 7 of 28 px fragments (frag f: row=f/14, col=(f%14)*16)
    int l15 = lane & 15;
    int kchunk = (lane >> 4) << 3;
    #pragma unroll
    for (int s = 0; s < 9; ++s) {
        int kh = s / 3, kw = s - kh * 3;
        #pragma unroll
        for (int i = 0; i < 7; ++i) {
            int f = wid * 7 + i;
            int row = (f >= 14) ? 1 : 0;
            int colf = (f - 14 * row) << 4;
            bf16x8 X = *reinterpret_cast<const bf16x8*>(
                &xs[((row + kh) * 226 + colf + l15 + kw) * PXS + kchunk]);
            acc[i][0] = __builtin_amdgcn_mfma_f32_16x16x32_bf16(Wf[s][0], X, acc[i][0], 0, 0, 0);
            acc[i][1] = __builtin_amdgcn_mfma_f32_16x16x32_bf16(Wf[s][1], X, acc[i][1], 0, 0, 0);
        }
    }
    __syncthreads();   // all xs reads done; lraw becomes ot

    // acc -> ot[co][px448]   (2-way bank aliasing only)
    #pragma unroll
    for (int i = 0; i < 7; ++i) {
        int f = wid * 7 + i;
        int row = (f >= 14) ? 1 : 0;
        int px = row * 224 + ((f - 14 * row) << 4) + l15;
        #pragma unroll
        for (int hf = 0; hf < 2; ++hf)
            #pragma unroll
            for (int r = 0; r < 4; ++r)
                ot[(hf * 16 + m4 + r) * COS + px] = acc[i][hf][r];
    }
    __syncthreads();

    // scales for full groups: 32 co x up to 12 groups
    #pragma unroll
    for (int it = 0; it < 2; ++it) {
        int task = tid + it * 256;
        if (task < 384) {
            int co = ((task >> 2) * 683) >> 11;          // task/12 = (task>>2)/3
            int k = task - co * 12;
            int base = rel0s[co] + 36 * k;
            if (base < bnds[co]) {
                const float* pp = &ot[co * COS + base];
                float m = 0.f;
                #pragma unroll
                for (int i = 0; i < 9; ++i) {
                    f32x4 vv = *reinterpret_cast<const f32x4*>(pp + 4 * i);
                    m = fmaxf(m, fmaxf(fmaxf(fabsf(vv[0]), fabsf(vv[1])),
                                       fmaxf(fabsf(vv[2]), fabsf(vv[3]))));
                }
                scl[co * 12 + k] = (m > 0.f) ? scale_from_max(m) : 0.f;
            }
        }
    }
    __syncthreads();

    // quantize + store: 3584 f32x4 chunks; each chunk lies in ONE group
    float* ob = out + (size_t)(b * 32) * HWp + h0 * 224;
    #pragma unroll
    for (int j = 0; j < 14; ++j) {
        int idx = tid + j * 256;
        int co = ((idx >> 4) * 2341) >> 14;              // idx/112 = (idx>>4)/7
        int c4 = idx - co * 112;
        int px0 = c4 * 4;
        f32x4 v = *reinterpret_cast<const f32x4*>(&ot[co * COS + px0]);
        int rz = px0 - rel0s[co];
        if ((unsigned)rz < (unsigned)(bnds[co] - rel0s[co])) {   // full-group zone
            int k = (int)div36((unsigned)rz);
            float s = scl[co * 12 + k];
            if (s > 0.f) {
                float inv = inv_from_scale(s);
                #pragma unroll
                for (int e = 0; e < 4; ++e) v[e] = rintf(v[e] * inv) * s;
            } else {
                v = f32x4{0.f, 0.f, 0.f, 0.f};
            }
        }
        // else: straddle zone -> raw value, k_fixup quantizes later
        *reinterpret_cast<f32x4*>(ob + (size_t)co * HWp + px0) = v;
    }
}

// ---------- fixup: quantize the 448-boundary-straddling groups in place ----------
// Straddle groups: g mod 112 in {12,24,37,49,62,74,87,99} (8 per 112).
__global__ __launch_bounds__(256) void k_fixup(float* __restrict__ buf) {
    int i = blockIdx.x * 256 + threadIdx.x;
    if (i >= 50976) return;
    const unsigned long long SP =
        12ull | (24ull << 7) | (37ull << 14) | (49ull << 21) |
        (62ull << 28) | (74ull << 35) | (87ull << 42) | (99ull << 49);
    int g = (i >> 3) * 112 + (int)((SP >> (7 * (i & 7))) & 127ull);
    if (g >= GXN) return;
    int f4 = 9 * g;                       // 36g/4
    f32x4 v[9];
    float m = 0.f;
    #pragma unroll
    for (int k = 0; k < 9; ++k) {
        f32x4 tv = {0.f, 0.f, 0.f, 0.f};
        if ((unsigned)(f4 + k) < (unsigned)NX4)
            tv = reinterpret_cast<const f32x4*>(buf)[f4 + k];
        v[k] = tv;
        m = fmaxf(m, fmaxf(fmaxf(fabsf(tv[0]), fabsf(tv[1])),
                           fmaxf(fabsf(tv[2]), fabsf(tv[3]))));
    }
    if (m > 0.f) {
        float s = scale_from_max(m), inv = inv_from_scale(s);
        #pragma unroll
        for (int k = 0; k < 9; ++k) {
            #pragma unroll
            for (int e = 0; e < 4; ++e) v[k][e] = rintf(v[k][e] * inv) * s;
            if ((unsigned)(f4 + k) < (unsigned)NX4)
                reinterpret_cast<f32x4*>(buf)[f4 + k] = v[k];
        }
    }
}

extern "C" void kernel_launch(void* const* d_in, const int* in_sizes, int n_in,
                              void* d_out, int out_size, void* d_ws, size_t ws_size,
                              hipStream_t stream) {
    (void)in_sizes; (void)n_in; (void)out_size; (void)ws_size;
    const float* x    = (const float*)d_in[0];
    const float* w    = (const float*)d_in[1];
    const float* bias = (const float*)d_in[2];
    float* out        = (float*)d_out;

    unsigned short* xt = (unsigned short*)d_ws;   // NX bf16 NHWC (51.4 MB)
    unsigned short* wt = xt + NX;                 // 9,216 bf16

    k_quant_x_fused<<<dim3(224, 16), 256, 0, stream>>>(x, xt, w, wt);
    k_conv_q<<<dim3(112, 16), 256, 0, stream>>>(xt, wt, bias, out);
    k_fixup<<<200, 256, 0, stream>>>(out);        // 50,976 straddle-group slots
}